// Round 1
// baseline (851.123 us; speedup 1.0000x reference)
//
#include <hip/hip_runtime.h>
#include <math.h>

// Problem constants (fixed by reference)
#define BB 2
#define LL 2048
#define HH 16
#define EE 64
#define LDP 68   // padded LDS leading dim (floats)

// ---------------------------------------------------------------------------
// Kernel 1: causal flash attention, fp32.
// grid: B*H*(L/64) blocks of 256 threads. Block handles 64 query rows for one
// (b,h). Online softmax over 64-wide KV tiles. Writes out[b,l,h,d].
// ---------------------------------------------------------------------------
__global__ __launch_bounds__(256) void attn_kernel(
    const float* __restrict__ q, const float* __restrict__ k,
    const float* __restrict__ v, float* __restrict__ out)
{
    __shared__ float Qs[EE][LDP];   // Q^T: Qs[e][r]
    __shared__ float KPs[64][LDP];  // K^T: KPs[e][c], later reused as P^T: KPs[s][r]
    __shared__ float Vs[64][LDP];   // V: Vs[s][d]

    const int tid = threadIdx.x;
    const int ty = tid >> 4;        // 0..15 -> query sub-rows
    const int tx = tid & 15;        // 0..15 -> col sub-tiles
    const int bid = blockIdx.x;
    const int qt = bid & 31;        // query tile
    const int h  = (bid >> 5) & 15;
    const int b  = bid >> 9;

    const int q0 = qt * 64;
    const float scale = 0.125f;     // 1/sqrt(64)

    // ---- load Q tile transposed into LDS (coalesced float4 reads) ----
    {
        const float* qbase = q + (((b * LL + q0) * HH) + h) * EE;
        #pragma unroll
        for (int i = 0; i < 4; ++i) {
            int lin = (i * 256 + tid) * 4;  // [0,4096)
            int r  = lin >> 6;
            int e0 = lin & 63;
            float4 val = *(const float4*)(qbase + r * (HH * EE) + e0);
            Qs[e0 + 0][r] = val.x;
            Qs[e0 + 1][r] = val.y;
            Qs[e0 + 2][r] = val.z;
            Qs[e0 + 3][r] = val.w;
        }
    }

    float acc[4][4] = {};
    float m_i[4], l_i[4];
    #pragma unroll
    for (int i = 0; i < 4; ++i) { m_i[i] = -INFINITY; l_i[i] = 0.f; }

    const float* kbase = k + ((b * LL) * HH + h) * EE;
    const float* vbase = v + ((b * LL) * HH + h) * EE;

    for (int j = 0; j <= qt; ++j) {
        const int s0 = j * 64;
        const bool diag = (j == qt);

        __syncthreads();  // prior iter's reads of KPs/Vs complete
        // ---- stage K^T and V tiles ----
        #pragma unroll
        for (int i = 0; i < 4; ++i) {
            int lin = (i * 256 + tid) * 4;
            int r  = lin >> 6;   // row within tile (s)
            int e0 = lin & 63;   // e / d
            float4 kv4 = *(const float4*)(kbase + (s0 + r) * (HH * EE) + e0);
            KPs[e0 + 0][r] = kv4.x;
            KPs[e0 + 1][r] = kv4.y;
            KPs[e0 + 2][r] = kv4.z;
            KPs[e0 + 3][r] = kv4.w;
            float4 vv4 = *(const float4*)(vbase + (s0 + r) * (HH * EE) + e0);
            *(float4*)&Vs[r][e0] = vv4;
        }
        __syncthreads();

        // ---- S = Q @ K^T (4x4 micro-tile per thread) ----
        float s_acc[4][4] = {};
        #pragma unroll 8
        for (int e = 0; e < 64; ++e) {
            float4 a  = *(const float4*)&Qs[e][ty * 4];
            float4 bb = *(const float4*)&KPs[e][tx * 4];
            float av[4] = {a.x, a.y, a.z, a.w};
            float bv[4] = {bb.x, bb.y, bb.z, bb.w};
            #pragma unroll
            for (int i = 0; i < 4; ++i)
                #pragma unroll
                for (int jj = 0; jj < 4; ++jj)
                    s_acc[i][jj] = fmaf(av[i], bv[jj], s_acc[i][jj]);
        }

        // ---- online softmax update (row stats across 16-lane groups) ----
        float p[4][4];
        float alpha[4];
        #pragma unroll
        for (int i = 0; i < 4; ++i) {
            int rloc = ty * 4 + i;
            #pragma unroll
            for (int jj = 0; jj < 4; ++jj) {
                float t = s_acc[i][jj] * scale;
                if (diag && (tx * 4 + jj) > rloc) t = -INFINITY;
                s_acc[i][jj] = t;
            }
            float mm = fmaxf(fmaxf(s_acc[i][0], s_acc[i][1]),
                             fmaxf(s_acc[i][2], s_acc[i][3]));
            #pragma unroll
            for (int mask = 1; mask < 16; mask <<= 1)
                mm = fmaxf(mm, __shfl_xor(mm, mask));
            float mnew = fmaxf(m_i[i], mm);
            float rs = 0.f;
            #pragma unroll
            for (int jj = 0; jj < 4; ++jj) {
                float pe = __expf(s_acc[i][jj] - mnew);
                p[i][jj] = pe;
                rs += pe;
            }
            #pragma unroll
            for (int mask = 1; mask < 16; mask <<= 1)
                rs += __shfl_xor(rs, mask);
            float al = __expf(m_i[i] - mnew);
            l_i[i] = l_i[i] * al + rs;
            m_i[i] = mnew;
            alpha[i] = al;
        }
        #pragma unroll
        for (int i = 0; i < 4; ++i)
            #pragma unroll
            for (int jj = 0; jj < 4; ++jj)
                acc[i][jj] *= alpha[i];

        __syncthreads();  // everyone done reading KPs (K^T)
        // ---- write P^T into KPs ----
        #pragma unroll
        for (int i = 0; i < 4; ++i)
            #pragma unroll
            for (int jj = 0; jj < 4; ++jj)
                KPs[tx * 4 + jj][ty * 4 + i] = p[i][jj];
        __syncthreads();

        // ---- O += P @ V ----
        #pragma unroll 8
        for (int s = 0; s < 64; ++s) {
            float4 pp = *(const float4*)&KPs[s][ty * 4];
            float4 vv = *(const float4*)&Vs[s][tx * 4];
            float pv[4] = {pp.x, pp.y, pp.z, pp.w};
            float vvv[4] = {vv.x, vv.y, vv.z, vv.w};
            #pragma unroll
            for (int i = 0; i < 4; ++i)
                #pragma unroll
                for (int jj = 0; jj < 4; ++jj)
                    acc[i][jj] = fmaf(pv[i], vvv[jj], acc[i][jj]);
        }
    }

    // ---- epilogue: normalize and store ----
    #pragma unroll
    for (int i = 0; i < 4; ++i) {
        float inv = 1.f / l_i[i];
        float4 o;
        o.x = acc[i][0] * inv;
        o.y = acc[i][1] * inv;
        o.z = acc[i][2] * inv;
        o.w = acc[i][3] * inv;
        int row = q0 + ty * 4 + i;
        *(float4*)(out + ((b * LL + row) * HH + h) * EE + tx * 4) = o;
    }
}

// ---------------------------------------------------------------------------
// Kernel 2: out += 0.1 * init_score @ V   (full, unmasked)
// Per batch: [2048 x 2048] @ [2048 x 1024]. grid: B*(2048/64)*(1024/64)=1024
// blocks of 256 threads, 64x64x64 tiles, 4x4 micro-tile.
// ---------------------------------------------------------------------------
__global__ __launch_bounds__(256) void bias_kernel(
    const float* __restrict__ isc, const float* __restrict__ v,
    float* __restrict__ out)
{
    __shared__ float As[64][LDP];  // IS^T: As[kk][m]
    __shared__ float Bs[64][LDP];  // V:    Bs[kk][n]

    const int tid = threadIdx.x;
    const int ty = tid >> 4;
    const int tx = tid & 15;
    const int bid = blockIdx.x;
    const int nt = bid & 15;          // 1024/64 = 16 col tiles
    const int mt = (bid >> 4) & 31;   // 2048/64 = 32 row tiles
    const int b  = bid >> 9;

    const int m0 = mt * 64, n0 = nt * 64;
    const float* abase = isc + (b * LL + m0) * LL;     // IS[b][m0+..][..]
    const float* bbase = v + (b * LL) * (HH * EE) + n0; // V[b][..][n0+..]

    float acc[4][4] = {};

    for (int kt = 0; kt < 32; ++kt) {
        const int k0 = kt * 64;
        __syncthreads();
        #pragma unroll
        for (int i = 0; i < 4; ++i) {
            int lin = (i * 256 + tid) * 4;
            int r  = lin >> 6;   // m for A, kk for B
            int c0 = lin & 63;   // kk for A, n for B
            float4 a4 = *(const float4*)(abase + r * LL + k0 + c0);
            As[c0 + 0][r] = a4.x;
            As[c0 + 1][r] = a4.y;
            As[c0 + 2][r] = a4.z;
            As[c0 + 3][r] = a4.w;
            float4 b4 = *(const float4*)(bbase + (k0 + r) * (HH * EE) + c0);
            *(float4*)&Bs[r][c0] = b4;
        }
        __syncthreads();

        #pragma unroll 8
        for (int kk = 0; kk < 64; ++kk) {
            float4 a  = *(const float4*)&As[kk][ty * 4];
            float4 bb = *(const float4*)&Bs[kk][tx * 4];
            float av[4] = {a.x, a.y, a.z, a.w};
            float bv[4] = {bb.x, bb.y, bb.z, bb.w};
            #pragma unroll
            for (int i = 0; i < 4; ++i)
                #pragma unroll
                for (int jj = 0; jj < 4; ++jj)
                    acc[i][jj] = fmaf(av[i], bv[jj], acc[i][jj]);
        }
    }

    // out += 0.1 * acc (attention kernel already wrote out)
    #pragma unroll
    for (int i = 0; i < 4; ++i) {
        float* optr = out + (b * LL + m0 + ty * 4 + i) * (HH * EE) + n0 + tx * 4;
        float4 o = *(float4*)optr;
        o.x += 0.1f * acc[i][0];
        o.y += 0.1f * acc[i][1];
        o.z += 0.1f * acc[i][2];
        o.w += 0.1f * acc[i][3];
        *(float4*)optr = o;
    }
}

extern "C" void kernel_launch(void* const* d_in, const int* in_sizes, int n_in,
                              void* d_out, int out_size, void* d_ws, size_t ws_size,
                              hipStream_t stream) {
    (void)in_sizes; (void)n_in; (void)out_size; (void)d_ws; (void)ws_size;
    const float* q   = (const float*)d_in[0];
    const float* k   = (const float*)d_in[1];
    const float* v   = (const float*)d_in[2];
    // d_in[3] = attn_mask: fixed causal triu, applied analytically
    const float* isc = (const float*)d_in[4];
    float* out = (float*)d_out;

    attn_kernel<<<dim3(BB * HH * (LL / 64)), dim3(256), 0, stream>>>(q, k, v, out);
    bias_kernel<<<dim3(BB * (LL / 64) * (HH * EE / 64)), dim3(256), 0, stream>>>(isc, v, out);
}

// Round 2
// 354.609 us; speedup vs baseline: 2.4002x; 2.4002x over previous
//
#include <hip/hip_runtime.h>
#include <hip/hip_bf16.h>
#include <math.h>

#define BB 2
#define LL 2048
#define HH 16
#define EE 64
#define STR 72   // LDS row stride in bf16 units (144 B, 16B-aligned rows)

typedef __attribute__((ext_vector_type(8))) short short8;
typedef __attribute__((ext_vector_type(4))) float floatx4;

__device__ inline unsigned short f2bf1(float f) {
    union { __hip_bfloat16 h; unsigned short u; } c;
    c.h = __float2bfloat16(f);
    return c.u;
}

__device__ inline ushort4 cvt4(float4 v) {
    union { __hip_bfloat162 h; unsigned int u; } a, b;
    a.h = __float22bfloat162_rn(make_float2(v.x, v.y));
    b.h = __float22bfloat162_rn(make_float2(v.z, v.w));
    ushort4 r;
    r.x = (unsigned short)(a.u & 0xffffu);
    r.y = (unsigned short)(a.u >> 16);
    r.z = (unsigned short)(b.u & 0xffffu);
    r.w = (unsigned short)(b.u >> 16);
    return r;
}

// ---------------------------------------------------------------------------
// Kernel 1: causal flash attention, bf16 MFMA (16x16x32), fp32 accumulate.
// Block = 256 thr (4 waves), 64 q-rows per (b,h). KV tiles of 64.
// ---------------------------------------------------------------------------
__global__ __launch_bounds__(256, 4) void attn_mfma(
    const float* __restrict__ q, const float* __restrict__ k,
    const float* __restrict__ v, float* __restrict__ out)
{
    __shared__ unsigned short Qs[64 * STR];      // Qs[m][e]
    __shared__ unsigned short Ks[64 * STR];      // Ks[s][e]
    __shared__ unsigned short Vt[64 * STR];      // Vt[d][s]  (V transposed)
    __shared__ unsigned short Ps[4][16 * STR];   // per-wave P[m][s]

    const int tid  = threadIdx.x;
    const int lane = tid & 63;
    const int wave = tid >> 6;
    const int lq   = lane >> 4;   // quad 0..3
    const int ln   = lane & 15;

    const int bid = blockIdx.x;
    const int qt  = 31 - (bid >> 5);   // longest blocks dispatch first
    const int h   = bid & 15;
    const int b   = (bid >> 4) & 1;
    const int q0  = qt * 64;

    const float* qbase = q + ((b * LL + q0) * HH + h) * EE;
    const float* kbase = k + ((b * LL) * HH + h) * EE;
    const float* vbase = v + ((b * LL) * HH + h) * EE;

    // ---- stage Q tile (64x64) as bf16, row-major ----
    #pragma unroll
    for (int i = 0; i < 4; ++i) {
        int lin = (i * 256 + tid) * 4;
        int r = lin >> 6, c = lin & 63;
        float4 v4 = *(const float4*)(qbase + r * (HH * EE) + c);
        *(ushort4*)&Qs[r * STR + c] = cvt4(v4);
    }
    __syncthreads();

    // Q A-frags for this wave's 16 rows (persist across KV loop)
    short8 qfrag[2];
    #pragma unroll
    for (int kk = 0; kk < 2; ++kk)
        qfrag[kk] = *(const short8*)&Qs[(wave * 16 + ln) * STR + kk * 32 + lq * 8];

    floatx4 zero = {0.f, 0.f, 0.f, 0.f};
    floatx4 o_acc[4];
    #pragma unroll
    for (int nt = 0; nt < 4; ++nt) o_acc[nt] = zero;
    float m_i[4], l_i[4];
    #pragma unroll
    for (int r = 0; r < 4; ++r) { m_i[r] = -INFINITY; l_i[r] = 0.f; }

    for (int j = 0; j <= qt; ++j) {
        const int s0 = j * 64;
        __syncthreads();   // prior iter's frag reads of Ks/Vt complete

        // ---- stage K tile row-major ----
        #pragma unroll
        for (int i = 0; i < 4; ++i) {
            int lin = (i * 256 + tid) * 4;
            int r = lin >> 6, c = lin & 63;
            float4 kv = *(const float4*)(kbase + (s0 + r) * (HH * EE) + c);
            *(ushort4*)&Ks[r * STR + c] = cvt4(kv);
        }
        // ---- stage V transposed: Vt[d][s] via 4x4 register transpose ----
        {
            int sb = (tid >> 4) * 4;
            int db = (tid & 15) * 4;
            ushort4 r0 = cvt4(*(const float4*)(vbase + (s0 + sb + 0) * (HH * EE) + db));
            ushort4 r1 = cvt4(*(const float4*)(vbase + (s0 + sb + 1) * (HH * EE) + db));
            ushort4 r2 = cvt4(*(const float4*)(vbase + (s0 + sb + 2) * (HH * EE) + db));
            ushort4 r3 = cvt4(*(const float4*)(vbase + (s0 + sb + 3) * (HH * EE) + db));
            *(ushort4*)&Vt[(db + 0) * STR + sb] = make_ushort4(r0.x, r1.x, r2.x, r3.x);
            *(ushort4*)&Vt[(db + 1) * STR + sb] = make_ushort4(r0.y, r1.y, r2.y, r3.y);
            *(ushort4*)&Vt[(db + 2) * STR + sb] = make_ushort4(r0.z, r1.z, r2.z, r3.z);
            *(ushort4*)&Vt[(db + 3) * STR + sb] = make_ushort4(r0.w, r1.w, r2.w, r3.w);
        }
        __syncthreads();

        // ---- S = Q @ K^T : 8 mfma ----
        floatx4 s_acc[4];
        #pragma unroll
        for (int nt = 0; nt < 4; ++nt) s_acc[nt] = zero;
        #pragma unroll
        for (int nt = 0; nt < 4; ++nt) {
            #pragma unroll
            for (int kk = 0; kk < 2; ++kk) {
                short8 kf = *(const short8*)&Ks[(nt * 16 + ln) * STR + kk * 32 + lq * 8];
                s_acc[nt] = __builtin_amdgcn_mfma_f32_16x16x32_bf16(qfrag[kk], kf, s_acc[nt], 0, 0, 0);
            }
        }

        // ---- online softmax (C layout: row = lq*4+r, col = nt*16+ln) ----
        const bool diag = (j == qt);
        float alphas[4];
        unsigned short* Pw = &Ps[wave][0];
        #pragma unroll
        for (int r = 0; r < 4; ++r) {
            const int myrow = wave * 16 + lq * 4 + r;
            float sv[4];
            #pragma unroll
            for (int nt = 0; nt < 4; ++nt) {
                float t = s_acc[nt][r] * 0.125f;
                if (diag && (nt * 16 + ln) > myrow) t = -INFINITY;
                sv[nt] = t;
            }
            float mm = fmaxf(fmaxf(sv[0], sv[1]), fmaxf(sv[2], sv[3]));
            mm = fmaxf(mm, __shfl_xor(mm, 1));
            mm = fmaxf(mm, __shfl_xor(mm, 2));
            mm = fmaxf(mm, __shfl_xor(mm, 4));
            mm = fmaxf(mm, __shfl_xor(mm, 8));
            float mnew = fmaxf(m_i[r], mm);
            float al = __expf(m_i[r] - mnew);
            float rs = 0.f;
            #pragma unroll
            for (int nt = 0; nt < 4; ++nt) {
                float pe = __expf(sv[nt] - mnew);
                rs += pe;
                Pw[(lq * 4 + r) * STR + nt * 16 + ln] = f2bf1(pe);
            }
            rs += __shfl_xor(rs, 1);
            rs += __shfl_xor(rs, 2);
            rs += __shfl_xor(rs, 4);
            rs += __shfl_xor(rs, 8);
            l_i[r] = l_i[r] * al + rs;
            m_i[r] = mnew;
            alphas[r] = al;
        }
        #pragma unroll
        for (int nt = 0; nt < 4; ++nt)
            #pragma unroll
            for (int r = 0; r < 4; ++r)
                o_acc[nt][r] *= alphas[r];

        // ---- O += P @ V : P from wave-private LDS (A layout), V^T as B ----
        short8 pf[2];
        pf[0] = *(const short8*)&Pw[ln * STR + lq * 8];
        pf[1] = *(const short8*)&Pw[ln * STR + 32 + lq * 8];
        #pragma unroll
        for (int nt = 0; nt < 4; ++nt) {
            #pragma unroll
            for (int kk = 0; kk < 2; ++kk) {
                short8 vf = *(const short8*)&Vt[(nt * 16 + ln) * STR + kk * 32 + lq * 8];
                o_acc[nt] = __builtin_amdgcn_mfma_f32_16x16x32_bf16(pf[kk], vf, o_acc[nt], 0, 0, 0);
            }
        }
    }

    // ---- epilogue ----
    #pragma unroll
    for (int r = 0; r < 4; ++r) {
        float inv = 1.0f / l_i[r];
        int row = q0 + wave * 16 + lq * 4 + r;
        float* obase = out + ((b * LL + row) * HH + h) * EE;
        #pragma unroll
        for (int nt = 0; nt < 4; ++nt)
            obase[nt * 16 + ln] = o_acc[nt][r] * inv;
    }
}

// ---------------------------------------------------------------------------
// Kernel 2: out += 0.1 * IS @ V.  bf16 MFMA GEMM, 128x128 tile, BK=64.
// M=2048, N=1024 (h*64+d contiguous), K=2048. Grid 2*16*8 = 256 blocks.
// ---------------------------------------------------------------------------
__global__ __launch_bounds__(256, 2) void bias_mfma(
    const float* __restrict__ isc, const float* __restrict__ v,
    float* __restrict__ out)
{
    __shared__ unsigned short As[128 * STR];  // As[m][k]
    __shared__ unsigned short Bt[128 * STR];  // Bt[n][k]  (V transposed)

    const int tid  = threadIdx.x;
    const int lane = tid & 63;
    const int wave = tid >> 6;
    const int lq   = lane >> 4;
    const int ln   = lane & 15;

    const int bid = blockIdx.x;
    const int ntb = bid & 7;
    const int mt  = (bid >> 3) & 15;
    const int b   = bid >> 7;
    const int m0  = mt * 128;
    const int n0  = ntb * 128;
    const int wm  = (wave >> 1) * 64;
    const int wn  = (wave & 1) * 64;

    const float* abase = isc + (b * LL + m0) * LL;
    const float* bbase = v + (b * LL) * (HH * EE) + n0;

    floatx4 zero = {0.f, 0.f, 0.f, 0.f};
    floatx4 acc[4][4];
    #pragma unroll
    for (int i = 0; i < 4; ++i)
        #pragma unroll
        for (int jn = 0; jn < 4; ++jn) acc[i][jn] = zero;

    for (int kt = 0; kt < 32; ++kt) {
        const int k0 = kt * 64;
        __syncthreads();
        // stage A: 128 rows x 64 k, row-major bf16
        #pragma unroll
        for (int i = 0; i < 8; ++i) {
            int lin = (i * 256 + tid) * 4;
            int r = lin >> 6, c = lin & 63;
            float4 a4 = *(const float4*)(abase + r * LL + k0 + c);
            *(ushort4*)&As[r * STR + c] = cvt4(a4);
        }
        // stage B^T: 64 k x 128 n -> Bt[n][k] via 4x4 register transpose
        {
            int nb  = (tid & 31) * 4;
            int kb0 = (tid >> 5) * 4;
            #pragma unroll
            for (int half = 0; half < 2; ++half) {
                int kb = kb0 + half * 32;
                ushort4 r0 = cvt4(*(const float4*)(bbase + (k0 + kb + 0) * (HH * EE) + nb));
                ushort4 r1 = cvt4(*(const float4*)(bbase + (k0 + kb + 1) * (HH * EE) + nb));
                ushort4 r2 = cvt4(*(const float4*)(bbase + (k0 + kb + 2) * (HH * EE) + nb));
                ushort4 r3 = cvt4(*(const float4*)(bbase + (k0 + kb + 3) * (HH * EE) + nb));
                *(ushort4*)&Bt[(nb + 0) * STR + kb] = make_ushort4(r0.x, r1.x, r2.x, r3.x);
                *(ushort4*)&Bt[(nb + 1) * STR + kb] = make_ushort4(r0.y, r1.y, r2.y, r3.y);
                *(ushort4*)&Bt[(nb + 2) * STR + kb] = make_ushort4(r0.z, r1.z, r2.z, r3.z);
                *(ushort4*)&Bt[(nb + 3) * STR + kb] = make_ushort4(r0.w, r1.w, r2.w, r3.w);
            }
        }
        __syncthreads();

        #pragma unroll
        for (int kk = 0; kk < 2; ++kk) {
            short8 af[4], bf[4];
            #pragma unroll
            for (int i = 0; i < 4; ++i)
                af[i] = *(const short8*)&As[(wm + i * 16 + ln) * STR + kk * 32 + lq * 8];
            #pragma unroll
            for (int jn = 0; jn < 4; ++jn)
                bf[jn] = *(const short8*)&Bt[(wn + jn * 16 + ln) * STR + kk * 32 + lq * 8];
            #pragma unroll
            for (int i = 0; i < 4; ++i)
                #pragma unroll
                for (int jn = 0; jn < 4; ++jn)
                    acc[i][jn] = __builtin_amdgcn_mfma_f32_16x16x32_bf16(af[i], bf[jn], acc[i][jn], 0, 0, 0);
        }
    }

    // epilogue: out += 0.1 * acc
    #pragma unroll
    for (int i = 0; i < 4; ++i) {
        #pragma unroll
        for (int r = 0; r < 4; ++r) {
            int row = m0 + wm + i * 16 + lq * 4 + r;
            float* op = out + (b * LL + row) * (HH * EE) + n0 + wn + ln;
            #pragma unroll
            for (int jn = 0; jn < 4; ++jn) {
                float* p = op + jn * 16;
                *p = *p + 0.1f * acc[i][jn][r];
            }
        }
    }
}

extern "C" void kernel_launch(void* const* d_in, const int* in_sizes, int n_in,
                              void* d_out, int out_size, void* d_ws, size_t ws_size,
                              hipStream_t stream) {
    (void)in_sizes; (void)n_in; (void)out_size; (void)d_ws; (void)ws_size;
    const float* q   = (const float*)d_in[0];
    const float* k   = (const float*)d_in[1];
    const float* v   = (const float*)d_in[2];
    // d_in[3] = attn_mask: fixed causal triu, applied analytically
    const float* isc = (const float*)d_in[4];
    float* out = (float*)d_out;

    attn_mfma<<<dim3(BB * HH * (LL / 64)), dim3(256), 0, stream>>>(q, k, v, out);
    bias_mfma<<<dim3(256), dim3(256), 0, stream>>>(isc, v, out);
}